// Round 5
// baseline (159.888 us; speedup 1.0000x reference)
//
#include <hip/hip_runtime.h>
#include <stdint.h>

#define N_TOK 16384
#define F_DIM 128
#define U_DIM 64
#define E_DIM 32

typedef __bf16 bf16x8 __attribute__((ext_vector_type(8)));
typedef float  floatx4 __attribute__((ext_vector_type(4)));

#define MFMA16(a, b, c) __builtin_amdgcn_mfma_f32_16x16x32_bf16((a), (b), (c), 0, 0, 0)

__device__ __forceinline__ unsigned short f2bf(float f) {
  union { float f; unsigned u; } v; v.f = f;
  unsigned r = v.u + 0x7FFFu + ((v.u >> 16) & 1u);  // RNE
  return (unsigned short)(r >> 16);
}

// ---------------------------------------------------------------------------
// Prep: fragment-linear bf16 weights in ws (verified layout).
//  wsWe elem idx: ((e*4+ks)*4+quad)*512 + u*8 + j   == We[e][ks*32+quad*8+j][u]
//  wsWg elem idx: ((et*4+ks)*64 + lane)*8 + j       == Wg[ks*32+(lane>>4)*8+j][et*16+(lane&15)]
// ---------------------------------------------------------------------------
__global__ __launch_bounds__(256) void moe_prep(
    const float* __restrict__ Wg, const float* __restrict__ We,
    unsigned short* __restrict__ wsWe, unsigned short* __restrict__ wsWg) {
  int t = blockIdx.x * 256 + threadIdx.x;
  if (t < 32768) {
    int u = t & 63, quad = (t >> 6) & 3, ks = (t >> 8) & 3, e = t >> 10;
    int f0 = ks * 32 + quad * 8;
    const float* src = We + e * 8192 + f0 * 64 + u;
    union { unsigned short us[8]; uint4 q; } p;
#pragma unroll
    for (int j = 0; j < 8; j++) p.us[j] = f2bf(src[j * 64]);
    *(uint4*)(wsWe + t * 8) = p.q;
  } else if (t < 32768 + 512) {
    int t2 = t - 32768;
    int l15 = t2 & 15, quad = (t2 >> 4) & 3, ks = (t2 >> 6) & 3, et = t2 >> 8;
    int e = et * 16 + l15, f0 = ks * 32 + quad * 8;
    union { unsigned short us[8]; uint4 q; } p;
#pragma unroll
    for (int j = 0; j < 8; j++) p.us[j] = f2bf(Wg[(f0 + j) * 32 + e]);
    *(uint4*)(wsWg + t2 * 8) = p.q;
  }
}

// ---------------------------------------------------------------------------
// Main: R1 structure (79.8 us measured) with ONE change: B register ring
// deepened 4->6, prefetch distance 3->5, prologue prefetches experts 0..4
// before X staging. Cold-miss tolerance rises from ~3 to ~5 iterations,
// riding out post-poison cold L2/L3 latency (~900-1400 cyc). Loop fully
// unrolled so all ring indices (e%6) are compile-time (no scratch).
// ---------------------------------------------------------------------------
__global__ __launch_bounds__(512, 2) void moe_main(
    const float* __restrict__ x,
    const float* __restrict__ bg,
    const float* __restrict__ be,
    const unsigned short* __restrict__ wsWe,
    const unsigned short* __restrict__ wsWg,
    float* __restrict__ out) {
  __shared__ unsigned short Xs[64 * 136];  // padded rows
  __shared__ float Gs[E_DIM][68];          // gate [e][row], padded

  const int tid  = threadIdx.x;
  const int lane = tid & 63;
  const int wid  = tid >> 6;       // 0..7
  const int quad = lane >> 4;
  const int l15  = lane & 15;
  const int wr   = wid >> 2;       // 0..1 row half
  const int wc   = wid & 3;        // 0..3 u quarter
  const int u    = wc * 16 + l15;
  const int base = blockIdx.x * 64;

  // ---- B ring: prefetch experts 0..4 (depth-5) before anything else.
  // Cold misses for these hide under X staging + gate (~2000 cyc).
  bf16x8 bbuf[6][4];
  float bevb[6];
#pragma unroll
  for (int e0 = 0; e0 < 5; e0++) {
#pragma unroll
    for (int ks = 0; ks < 4; ks++)
      bbuf[e0][ks] = *(const bf16x8*)(wsWe + (size_t)((e0 * 4 + ks) * 4 + quad) * 512 + u * 8);
    bevb[e0] = be[e0 * U_DIM + u];
  }

  // ---- stage X tile (fp32 -> bf16) into LDS: 512 thr x 16 floats = 64x128
  {
    const int row = tid >> 3;
    const int c16 = tid & 7;
    const float4* src = (const float4*)(x + (size_t)(base + row) * F_DIM + c16 * 16);
    float4 v0 = src[0], v1 = src[1], v2 = src[2], v3 = src[3];
    union { unsigned short us[16]; uint4 q[2]; } pk;
    pk.us[0]  = f2bf(v0.x); pk.us[1]  = f2bf(v0.y); pk.us[2]  = f2bf(v0.z); pk.us[3]  = f2bf(v0.w);
    pk.us[4]  = f2bf(v1.x); pk.us[5]  = f2bf(v1.y); pk.us[6]  = f2bf(v1.z); pk.us[7]  = f2bf(v1.w);
    pk.us[8]  = f2bf(v2.x); pk.us[9]  = f2bf(v2.y); pk.us[10] = f2bf(v2.z); pk.us[11] = f2bf(v2.w);
    pk.us[12] = f2bf(v3.x); pk.us[13] = f2bf(v3.y); pk.us[14] = f2bf(v3.z); pk.us[15] = f2bf(v3.w);
    uint4* dst = (uint4*)&Xs[row * 136 + c16 * 16];
    dst[0] = pk.q[0];
    dst[1] = pk.q[1];
  }
  __syncthreads();  // barrier 1: X ready

  // ---- gate: 8 waves, wave = (rowgroup rg, expert-half et)
  {
    const int rg = wid >> 1;   // 0..3 -> rows rg*16..
    const int et = wid & 1;    // 0..1 -> experts et*16..
    bf16x8 ag[4];
#pragma unroll
    for (int ks = 0; ks < 4; ks++)
      ag[ks] = *(const bf16x8*)&Xs[(rg * 16 + l15) * 136 + ks * 32 + quad * 8];
    floatx4 g = {0.f, 0.f, 0.f, 0.f};
#pragma unroll
    for (int ks = 0; ks < 4; ks++) {
      bf16x8 wb = *(const bf16x8*)(wsWg + (size_t)((et * 4 + ks) * 64 + lane) * 8);
      g = MFMA16(ag[ks], wb, g);
    }
    float bgv = bg[et * 16 + l15];
#pragma unroll
    for (int r = 0; r < 4; r++)
      Gs[et * 16 + l15][rg * 16 + quad * 4 + r] = g[r] + bgv;
  }

  // ---- preload this wave's A fragments (32 rows; X never re-read after)
  bf16x8 a[2][4];
#pragma unroll
  for (int mb = 0; mb < 2; mb++)
#pragma unroll
    for (int ks = 0; ks < 4; ks++)
      a[mb][ks] = *(const bf16x8*)&Xs[(wr * 32 + mb * 16 + l15) * 136 + ks * 32 + quad * 8];
  __syncthreads();  // barrier 2: Gs ready (last barrier)

  float oacc[8];
#pragma unroll
  for (int i = 0; i < 8; i++) oacc[i] = 0.f;

  // ---- gate double-buffer: preload e=0 as float4 rows
  float4 gbuf[2][2];
#pragma unroll
  for (int mb = 0; mb < 2; mb++)
    gbuf[0][mb] = *(const float4*)&Gs[0][wr * 32 + mb * 16 + quad * 4];

  // ---- expert loop: no barriers; FULL unroll so e%6 ring index is literal
#pragma unroll
  for (int e = 0; e < E_DIM; ++e) {
    const int c = e % 6;
    const int gp = e & 1;

    // prefetch B for e+5 into the slot last used by e-1 (consumed)
    if (e + 5 < E_DIM) {
      const int s = (e + 5) % 6;
#pragma unroll
      for (int ks = 0; ks < 4; ks++)
        bbuf[s][ks] =
            *(const bf16x8*)(wsWe + (size_t)(((e + 5) * 4 + ks) * 4 + quad) * 512 + u * 8);
      bevb[s] = be[(e + 5) * U_DIM + u];
    }
    // prefetch gate rows for e+1 (hidden under e's MFMAs)
    if (e + 1 < E_DIM) {
#pragma unroll
      for (int mb = 0; mb < 2; mb++)
        gbuf[gp ^ 1][mb] = *(const float4*)&Gs[e + 1][wr * 32 + mb * 16 + quad * 4];
    }

    const float bev = bevb[c];
    floatx4 h[2];
#pragma unroll
    for (int mb = 0; mb < 2; mb++) h[mb] = {bev, bev, bev, bev};
#pragma unroll
    for (int ks = 0; ks < 4; ks++)
#pragma unroll
      for (int mb = 0; mb < 2; mb++)
        h[mb] = MFMA16(a[mb][ks], bbuf[c][ks], h[mb]);

    // epilogue: out += gate * leaky(h),  leaky(t) = max(t, 0.01t)
#pragma unroll
    for (int mb = 0; mb < 2; mb++) {
      const float4 g4 = gbuf[gp][mb];
      const float gr[4] = {g4.x, g4.y, g4.z, g4.w};
#pragma unroll
      for (int r = 0; r < 4; r++) {
        float t = h[mb][r];
        t = fmaxf(t, 0.01f * t);
        oacc[mb * 4 + r] = fmaf(gr[r], t, oacc[mb * 4 + r]);
      }
    }
  }

  // ---- store
#pragma unroll
  for (int mb = 0; mb < 2; mb++)
#pragma unroll
    for (int r = 0; r < 4; r++)
      out[(size_t)(base + mb * 16 + wr * 32 + quad * 4 + r - mb * 16 + mb * 16) * U_DIM + u] = oacc[mb * 4 + r];
}

extern "C" void kernel_launch(void* const* d_in, const int* in_sizes, int n_in,
                              void* d_out, int out_size, void* d_ws, size_t ws_size,
                              hipStream_t stream) {
  const float* x  = (const float*)d_in[0];
  const float* Wg = (const float*)d_in[1];
  const float* bg = (const float*)d_in[2];
  const float* We = (const float*)d_in[3];
  const float* be = (const float*)d_in[4];
  unsigned short* wsWe = (unsigned short*)d_ws;              // 512 KB
  unsigned short* wsWg = wsWe + E_DIM * U_DIM * F_DIM;       // +8 KB
  (void)in_sizes; (void)n_in; (void)out_size; (void)ws_size;

  moe_prep<<<130, 256, 0, stream>>>(Wg, We, wsWe, wsWg);
  moe_main<<<N_TOK / 64, 512, 0, stream>>>(x, bg, be, wsWe, wsWg, (float*)d_out);
}

// Round 6
// 151.807 us; speedup vs baseline: 1.0532x; 1.0532x over previous
//
#include <hip/hip_runtime.h>
#include <stdint.h>

#define N_TOK 16384
#define F_DIM 128
#define U_DIM 64
#define E_DIM 32

typedef __bf16 bf16x8 __attribute__((ext_vector_type(8)));
typedef float  floatx4 __attribute__((ext_vector_type(4)));

#define MFMA16(a, b, c) __builtin_amdgcn_mfma_f32_16x16x32_bf16((a), (b), (c), 0, 0, 0)

__device__ __forceinline__ unsigned short f2bf(float f) {
  union { float f; unsigned u; } v; v.f = f;
  unsigned r = v.u + 0x7FFFu + ((v.u >> 16) & 1u);  // RNE
  return (unsigned short)(r >> 16);
}

// ---------------------------------------------------------------------------
// Prep: fragment-linear bf16 weights in ws (verified layout).
//  wsWe elem idx: ((e*4+ks)*4+quad)*512 + u*8 + j   == We[e][ks*32+quad*8+j][u]
//  wsWg elem idx: ((et*4+ks)*64 + lane)*8 + j       == Wg[ks*32+(lane>>4)*8+j][et*16+(lane&15)]
// ---------------------------------------------------------------------------
__global__ __launch_bounds__(256) void moe_prep(
    const float* __restrict__ Wg, const float* __restrict__ We,
    unsigned short* __restrict__ wsWe, unsigned short* __restrict__ wsWg) {
  int t = blockIdx.x * 256 + threadIdx.x;
  if (t < 32768) {
    int u = t & 63, quad = (t >> 6) & 3, ks = (t >> 8) & 3, e = t >> 10;
    int f0 = ks * 32 + quad * 8;
    const float* src = We + e * 8192 + f0 * 64 + u;
    union { unsigned short us[8]; uint4 q; } p;
#pragma unroll
    for (int j = 0; j < 8; j++) p.us[j] = f2bf(src[j * 64]);
    *(uint4*)(wsWe + t * 8) = p.q;
  } else if (t < 32768 + 512) {
    int t2 = t - 32768;
    int l15 = t2 & 15, quad = (t2 >> 4) & 3, ks = (t2 >> 6) & 3, et = t2 >> 8;
    int e = et * 16 + l15, f0 = ks * 32 + quad * 8;
    union { unsigned short us[8]; uint4 q; } p;
#pragma unroll
    for (int j = 0; j < 8; j++) p.us[j] = f2bf(Wg[(f0 + j) * 32 + e]);
    *(uint4*)(wsWg + t2 * 8) = p.q;
  }
}

// ---------------------------------------------------------------------------
// Main: R5 structure (depth-6 B ring, prefetch distance 5) with the VGPR cap
// FIXED: __launch_bounds__(512, 1). R5's (512,2) was honored as 2 blocks/CU
// -> 4 waves/SIMD -> 128-VGPR cap -> ~190-reg ring spilled to scratch
// (WRITE_SIZE 234 MB, 100 us). With 512-thread blocks 8 waves co-reside
// (2/SIMD) regardless, so cap rises to 256: no spills, same occupancy.
// ---------------------------------------------------------------------------
__global__ __launch_bounds__(512, 1) void moe_main(
    const float* __restrict__ x,
    const float* __restrict__ bg,
    const float* __restrict__ be,
    const unsigned short* __restrict__ wsWe,
    const unsigned short* __restrict__ wsWg,
    float* __restrict__ out) {
  __shared__ unsigned short Xs[64 * 136];  // padded rows
  __shared__ float Gs[E_DIM][68];          // gate [e][row], padded

  const int tid  = threadIdx.x;
  const int lane = tid & 63;
  const int wid  = tid >> 6;       // 0..7
  const int quad = lane >> 4;
  const int l15  = lane & 15;
  const int wr   = wid >> 2;       // 0..1 row half
  const int wc   = wid & 3;        // 0..3 u quarter
  const int u    = wc * 16 + l15;
  const int base = blockIdx.x * 64;

  // ---- B ring: prefetch experts 0..4 (depth-5 prologue) before anything.
  // Cold misses for these hide under X staging + gate (~2000 cyc).
  bf16x8 bbuf[6][4];
  float bevb[6];
#pragma unroll
  for (int e0 = 0; e0 < 5; e0++) {
#pragma unroll
    for (int ks = 0; ks < 4; ks++)
      bbuf[e0][ks] = *(const bf16x8*)(wsWe + (size_t)((e0 * 4 + ks) * 4 + quad) * 512 + u * 8);
    bevb[e0] = be[e0 * U_DIM + u];
  }

  // ---- stage X tile (fp32 -> bf16) into LDS: 512 thr x 16 floats = 64x128
  {
    const int row = tid >> 3;
    const int c16 = tid & 7;
    const float4* src = (const float4*)(x + (size_t)(base + row) * F_DIM + c16 * 16);
    float4 v0 = src[0], v1 = src[1], v2 = src[2], v3 = src[3];
    union { unsigned short us[16]; uint4 q[2]; } pk;
    pk.us[0]  = f2bf(v0.x); pk.us[1]  = f2bf(v0.y); pk.us[2]  = f2bf(v0.z); pk.us[3]  = f2bf(v0.w);
    pk.us[4]  = f2bf(v1.x); pk.us[5]  = f2bf(v1.y); pk.us[6]  = f2bf(v1.z); pk.us[7]  = f2bf(v1.w);
    pk.us[8]  = f2bf(v2.x); pk.us[9]  = f2bf(v2.y); pk.us[10] = f2bf(v2.z); pk.us[11] = f2bf(v2.w);
    pk.us[12] = f2bf(v3.x); pk.us[13] = f2bf(v3.y); pk.us[14] = f2bf(v3.z); pk.us[15] = f2bf(v3.w);
    uint4* dst = (uint4*)&Xs[row * 136 + c16 * 16];
    dst[0] = pk.q[0];
    dst[1] = pk.q[1];
  }
  __syncthreads();  // barrier 1: X ready

  // ---- gate: 8 waves, wave = (rowgroup rg, expert-half et)
  {
    const int rg = wid >> 1;   // 0..3 -> rows rg*16..
    const int et = wid & 1;    // 0..1 -> experts et*16..
    bf16x8 ag[4];
#pragma unroll
    for (int ks = 0; ks < 4; ks++)
      ag[ks] = *(const bf16x8*)&Xs[(rg * 16 + l15) * 136 + ks * 32 + quad * 8];
    floatx4 g = {0.f, 0.f, 0.f, 0.f};
#pragma unroll
    for (int ks = 0; ks < 4; ks++) {
      bf16x8 wb = *(const bf16x8*)(wsWg + (size_t)((et * 4 + ks) * 64 + lane) * 8);
      g = MFMA16(ag[ks], wb, g);
    }
    float bgv = bg[et * 16 + l15];
#pragma unroll
    for (int r = 0; r < 4; r++)
      Gs[et * 16 + l15][rg * 16 + quad * 4 + r] = g[r] + bgv;
  }

  // ---- preload this wave's A fragments (32 rows; X never re-read after)
  bf16x8 a[2][4];
#pragma unroll
  for (int mb = 0; mb < 2; mb++)
#pragma unroll
    for (int ks = 0; ks < 4; ks++)
      a[mb][ks] = *(const bf16x8*)&Xs[(wr * 32 + mb * 16 + l15) * 136 + ks * 32 + quad * 8];
  __syncthreads();  // barrier 2: Gs ready (last barrier)

  float oacc[8];
#pragma unroll
  for (int i = 0; i < 8; i++) oacc[i] = 0.f;

  // ---- gate double-buffer: preload e=0 as float4 rows
  float4 gbuf[2][2];
#pragma unroll
  for (int mb = 0; mb < 2; mb++)
    gbuf[0][mb] = *(const float4*)&Gs[0][wr * 32 + mb * 16 + quad * 4];

  // ---- expert loop: no barriers; FULL unroll so e%6 ring index is literal
#pragma unroll
  for (int e = 0; e < E_DIM; ++e) {
    const int c = e % 6;
    const int gp = e & 1;

    // prefetch B for e+5 into the slot last used by e-1 (consumed)
    if (e + 5 < E_DIM) {
      const int s = (e + 5) % 6;
#pragma unroll
      for (int ks = 0; ks < 4; ks++)
        bbuf[s][ks] =
            *(const bf16x8*)(wsWe + (size_t)(((e + 5) * 4 + ks) * 4 + quad) * 512 + u * 8);
      bevb[s] = be[(e + 5) * U_DIM + u];
    }
    // prefetch gate rows for e+1 (hidden under e's MFMAs)
    if (e + 1 < E_DIM) {
#pragma unroll
      for (int mb = 0; mb < 2; mb++)
        gbuf[gp ^ 1][mb] = *(const float4*)&Gs[e + 1][wr * 32 + mb * 16 + quad * 4];
    }

    const float bev = bevb[c];
    floatx4 h[2];
#pragma unroll
    for (int mb = 0; mb < 2; mb++) h[mb] = {bev, bev, bev, bev};
#pragma unroll
    for (int ks = 0; ks < 4; ks++)
#pragma unroll
      for (int mb = 0; mb < 2; mb++)
        h[mb] = MFMA16(a[mb][ks], bbuf[c][ks], h[mb]);

    // epilogue: out += gate * leaky(h),  leaky(t) = max(t, 0.01t)
#pragma unroll
    for (int mb = 0; mb < 2; mb++) {
      const float4 g4 = gbuf[gp][mb];
      const float gr[4] = {g4.x, g4.y, g4.z, g4.w};
#pragma unroll
      for (int r = 0; r < 4; r++) {
        float t = h[mb][r];
        t = fmaxf(t, 0.01f * t);
        oacc[mb * 4 + r] = fmaf(gr[r], t, oacc[mb * 4 + r]);
      }
    }
  }

  // ---- store
#pragma unroll
  for (int mb = 0; mb < 2; mb++)
#pragma unroll
    for (int r = 0; r < 4; r++)
      out[(size_t)(base + wr * 32 + mb * 16 + quad * 4 + r) * U_DIM + u] = oacc[mb * 4 + r];
}

extern "C" void kernel_launch(void* const* d_in, const int* in_sizes, int n_in,
                              void* d_out, int out_size, void* d_ws, size_t ws_size,
                              hipStream_t stream) {
  const float* x  = (const float*)d_in[0];
  const float* Wg = (const float*)d_in[1];
  const float* bg = (const float*)d_in[2];
  const float* We = (const float*)d_in[3];
  const float* be = (const float*)d_in[4];
  unsigned short* wsWe = (unsigned short*)d_ws;              // 512 KB
  unsigned short* wsWg = wsWe + E_DIM * U_DIM * F_DIM;       // +8 KB
  (void)in_sizes; (void)n_in; (void)out_size; (void)ws_size;

  moe_prep<<<130, 256, 0, stream>>>(Wg, We, wsWe, wsWg);
  moe_main<<<N_TOK / 64, 512, 0, stream>>>(x, bg, be, wsWe, wsWg, (float*)d_out);
}

// Round 7
// 122.310 us; speedup vs baseline: 1.3072x; 1.2412x over previous
//
#include <hip/hip_runtime.h>
#include <stdint.h>

#define N_TOK 16384
#define F_DIM 128
#define U_DIM 64
#define E_DIM 32

typedef __bf16 bf16x8 __attribute__((ext_vector_type(8)));
typedef float  floatx4 __attribute__((ext_vector_type(4)));

#define MFMA16(a, b, c) __builtin_amdgcn_mfma_f32_16x16x32_bf16((a), (b), (c), 0, 0, 0)

__device__ __forceinline__ unsigned short f2bf(float f) {
  union { float f; unsigned u; } v; v.f = f;
  unsigned r = v.u + 0x7FFFu + ((v.u >> 16) & 1u);  // RNE
  return (unsigned short)(r >> 16);
}

// ---------------------------------------------------------------------------
// Prep: fragment-linear bf16 weights in ws (verified layout).
//  wsWe elem idx: ((e*4+ks)*4+quad)*512 + u*8 + j   == We[e][ks*32+quad*8+j][u]
//  wsWg elem idx: ((et*4+ks)*64 + lane)*8 + j       == Wg[ks*32+(lane>>4)*8+j][et*16+(lane&15)]
// ---------------------------------------------------------------------------
__global__ __launch_bounds__(256) void moe_prep(
    const float* __restrict__ Wg, const float* __restrict__ We,
    unsigned short* __restrict__ wsWe, unsigned short* __restrict__ wsWg) {
  int t = blockIdx.x * 256 + threadIdx.x;
  if (t < 32768) {
    int u = t & 63, quad = (t >> 6) & 3, ks = (t >> 8) & 3, e = t >> 10;
    int f0 = ks * 32 + quad * 8;
    const float* src = We + e * 8192 + f0 * 64 + u;
    union { unsigned short us[8]; uint4 q; } p;
#pragma unroll
    for (int j = 0; j < 8; j++) p.us[j] = f2bf(src[j * 64]);
    *(uint4*)(wsWe + t * 8) = p.q;
  } else if (t < 32768 + 512) {
    int t2 = t - 32768;
    int l15 = t2 & 15, quad = (t2 >> 4) & 3, ks = (t2 >> 6) & 3, et = t2 >> 8;
    int e = et * 16 + l15, f0 = ks * 32 + quad * 8;
    union { unsigned short us[8]; uint4 q; } p;
#pragma unroll
    for (int j = 0; j < 8; j++) p.us[j] = f2bf(Wg[(f0 + j) * 32 + e]);
    *(uint4*)(wsWg + t2 * 8) = p.q;
  }
}

// ---------------------------------------------------------------------------
// Main: R1 structure with B register ring deepened 4 -> 8 using POWER-OF-2
// masking (e & 7) and #pragma unroll 8, so every ring index folds to a
// literal (known-bits) and SROA keeps bbuf in registers. R5/R6's "% 6" ring
// was demoted to scratch (VGPR 128, WRITE_SIZE 234 MB of spill traffic) —
// the &-mask + matching-unroll recipe is the one proven in R1 (&3/unroll 4).
// Prologue prefetches experts 0..6; in-loop prefetch distance 7 (~1400 cyc
// of cold-miss tolerance vs ~600 at the old distance 3).
// ---------------------------------------------------------------------------
__global__ __launch_bounds__(512, 1) void moe_main(
    const float* __restrict__ x,
    const float* __restrict__ bg,
    const float* __restrict__ be,
    const unsigned short* __restrict__ wsWe,
    const unsigned short* __restrict__ wsWg,
    float* __restrict__ out) {
  __shared__ unsigned short Xs[64 * 136];  // padded rows
  __shared__ float Gs[E_DIM][68];          // gate [e][row], padded

  const int tid  = threadIdx.x;
  const int lane = tid & 63;
  const int wid  = tid >> 6;       // 0..7
  const int quad = lane >> 4;
  const int l15  = lane & 15;
  const int wr   = wid >> 2;       // 0..1 row half
  const int wc   = wid & 3;        // 0..3 u quarter
  const int u    = wc * 16 + l15;
  const int base = blockIdx.x * 64;

  // ---- B ring: prefetch experts 0..6 (depth-7 prologue) before anything.
  // Cold misses for these hide under X staging + gate (~2000 cyc).
  bf16x8 bbuf[8][4];
  float bevb[8];
#pragma unroll
  for (int e0 = 0; e0 < 7; e0++) {
#pragma unroll
    for (int ks = 0; ks < 4; ks++)
      bbuf[e0][ks] = *(const bf16x8*)(wsWe + (size_t)((e0 * 4 + ks) * 4 + quad) * 512 + u * 8);
    bevb[e0] = be[e0 * U_DIM + u];
  }

  // ---- stage X tile (fp32 -> bf16) into LDS: 512 thr x 16 floats = 64x128
  {
    const int row = tid >> 3;
    const int c16 = tid & 7;
    const float4* src = (const float4*)(x + (size_t)(base + row) * F_DIM + c16 * 16);
    float4 v0 = src[0], v1 = src[1], v2 = src[2], v3 = src[3];
    union { unsigned short us[16]; uint4 q[2]; } pk;
    pk.us[0]  = f2bf(v0.x); pk.us[1]  = f2bf(v0.y); pk.us[2]  = f2bf(v0.z); pk.us[3]  = f2bf(v0.w);
    pk.us[4]  = f2bf(v1.x); pk.us[5]  = f2bf(v1.y); pk.us[6]  = f2bf(v1.z); pk.us[7]  = f2bf(v1.w);
    pk.us[8]  = f2bf(v2.x); pk.us[9]  = f2bf(v2.y); pk.us[10] = f2bf(v2.z); pk.us[11] = f2bf(v2.w);
    pk.us[12] = f2bf(v3.x); pk.us[13] = f2bf(v3.y); pk.us[14] = f2bf(v3.z); pk.us[15] = f2bf(v3.w);
    uint4* dst = (uint4*)&Xs[row * 136 + c16 * 16];
    dst[0] = pk.q[0];
    dst[1] = pk.q[1];
  }
  __syncthreads();  // barrier 1: X ready

  // ---- gate: 8 waves, wave = (rowgroup rg, expert-half et)
  {
    const int rg = wid >> 1;   // 0..3 -> rows rg*16..
    const int et = wid & 1;    // 0..1 -> experts et*16..
    bf16x8 ag[4];
#pragma unroll
    for (int ks = 0; ks < 4; ks++)
      ag[ks] = *(const bf16x8*)&Xs[(rg * 16 + l15) * 136 + ks * 32 + quad * 8];
    floatx4 g = {0.f, 0.f, 0.f, 0.f};
#pragma unroll
    for (int ks = 0; ks < 4; ks++) {
      bf16x8 wb = *(const bf16x8*)(wsWg + (size_t)((et * 4 + ks) * 64 + lane) * 8);
      g = MFMA16(ag[ks], wb, g);
    }
    float bgv = bg[et * 16 + l15];
#pragma unroll
    for (int r = 0; r < 4; r++)
      Gs[et * 16 + l15][rg * 16 + quad * 4 + r] = g[r] + bgv;
  }

  // ---- preload this wave's A fragments (32 rows; X never re-read after)
  bf16x8 a[2][4];
#pragma unroll
  for (int mb = 0; mb < 2; mb++)
#pragma unroll
    for (int ks = 0; ks < 4; ks++)
      a[mb][ks] = *(const bf16x8*)&Xs[(wr * 32 + mb * 16 + l15) * 136 + ks * 32 + quad * 8];
  __syncthreads();  // barrier 2: Gs ready (last barrier)

  float oacc[8];
#pragma unroll
  for (int i = 0; i < 8; i++) oacc[i] = 0.f;

  // ---- gate double-buffer: preload e=0 as float4 rows
  float4 gbuf[2][2];
#pragma unroll
  for (int mb = 0; mb < 2; mb++)
    gbuf[0][mb] = *(const float4*)&Gs[0][wr * 32 + mb * 16 + quad * 4];

  // ---- expert loop: no barriers; unroll 8 matches the &7 ring period so
  // every bbuf index is compile-time (SROA keeps the ring in VGPRs)
#pragma unroll 8
  for (int e = 0; e < E_DIM; ++e) {
    const int c = e & 7;
    const int gp = e & 1;

    // prefetch B for e+7 into the slot last used by e-1 (consumed)
    if (e + 7 < E_DIM) {
      const int s = (e + 7) & 7;
#pragma unroll
      for (int ks = 0; ks < 4; ks++)
        bbuf[s][ks] =
            *(const bf16x8*)(wsWe + (size_t)(((e + 7) * 4 + ks) * 4 + quad) * 512 + u * 8);
      bevb[s] = be[(e + 7) * U_DIM + u];
    }
    // prefetch gate rows for e+1 (hidden under e's MFMAs)
    if (e + 1 < E_DIM) {
#pragma unroll
      for (int mb = 0; mb < 2; mb++)
        gbuf[gp ^ 1][mb] = *(const float4*)&Gs[e + 1][wr * 32 + mb * 16 + quad * 4];
    }

    const float bev = bevb[c];
    floatx4 h[2];
#pragma unroll
    for (int mb = 0; mb < 2; mb++) h[mb] = {bev, bev, bev, bev};
#pragma unroll
    for (int ks = 0; ks < 4; ks++)
#pragma unroll
      for (int mb = 0; mb < 2; mb++)
        h[mb] = MFMA16(a[mb][ks], bbuf[c][ks], h[mb]);

    // epilogue: out += gate * leaky(h),  leaky(t) = max(t, 0.01t)
#pragma unroll
    for (int mb = 0; mb < 2; mb++) {
      const float4 g4 = gbuf[gp][mb];
      const float gr[4] = {g4.x, g4.y, g4.z, g4.w};
#pragma unroll
      for (int r = 0; r < 4; r++) {
        float t = h[mb][r];
        t = fmaxf(t, 0.01f * t);
        oacc[mb * 4 + r] = fmaf(gr[r], t, oacc[mb * 4 + r]);
      }
    }
  }

  // ---- store
#pragma unroll
  for (int mb = 0; mb < 2; mb++)
#pragma unroll
    for (int r = 0; r < 4; r++)
      out[(size_t)(base + wr * 32 + mb * 16 + quad * 4 + r) * U_DIM + u] = oacc[mb * 4 + r];
}

extern "C" void kernel_launch(void* const* d_in, const int* in_sizes, int n_in,
                              void* d_out, int out_size, void* d_ws, size_t ws_size,
                              hipStream_t stream) {
  const float* x  = (const float*)d_in[0];
  const float* Wg = (const float*)d_in[1];
  const float* bg = (const float*)d_in[2];
  const float* We = (const float*)d_in[3];
  const float* be = (const float*)d_in[4];
  unsigned short* wsWe = (unsigned short*)d_ws;              // 512 KB
  unsigned short* wsWg = wsWe + E_DIM * U_DIM * F_DIM;       // +8 KB
  (void)in_sizes; (void)n_in; (void)out_size; (void)ws_size;

  moe_prep<<<130, 256, 0, stream>>>(Wg, We, wsWe, wsWg);
  moe_main<<<N_TOK / 64, 512, 0, stream>>>(x, bg, be, wsWe, wsWg, (float*)d_out);
}

// Round 8
// 79.737 us; speedup vs baseline: 2.0052x; 1.5339x over previous
//
#include <hip/hip_runtime.h>
#include <stdint.h>

#define N_TOK 16384
#define F_DIM 128
#define U_DIM 64
#define E_DIM 32

typedef __bf16 bf16x8 __attribute__((ext_vector_type(8)));
typedef float  floatx4 __attribute__((ext_vector_type(4)));

#define MFMA16(a, b, c) __builtin_amdgcn_mfma_f32_16x16x32_bf16((a), (b), (c), 0, 0, 0)

__device__ __forceinline__ unsigned short f2bf(float f) {
  union { float f; unsigned u; } v; v.f = f;
  unsigned r = v.u + 0x7FFFu + ((v.u >> 16) & 1u);  // RNE
  return (unsigned short)(r >> 16);
}

// 16-byte global -> LDS direct DMA (no VGPR result, vmcnt-tracked)
__device__ __forceinline__ void gload_lds16(const void* g, void* l) {
  __builtin_amdgcn_global_load_lds(
      (const __attribute__((address_space(1))) unsigned int*)g,
      (__attribute__((address_space(3))) unsigned int*)l, 16, 0, 0);
}

// ---------------------------------------------------------------------------
// Prep: fragment-linear bf16 weights in ws (verified layout).
//  wsWe elem idx: ((e*4+ks)*4+quad)*512 + u*8 + j   == We[e][ks*32+quad*8+j][u]
//  wsWg elem idx: ((et*4+ks)*64 + lane)*8 + j       == Wg[ks*32+(lane>>4)*8+j][et*16+(lane&15)]
// ---------------------------------------------------------------------------
__global__ __launch_bounds__(256) void moe_prep(
    const float* __restrict__ Wg, const float* __restrict__ We,
    unsigned short* __restrict__ wsWe, unsigned short* __restrict__ wsWg) {
  int t = blockIdx.x * 256 + threadIdx.x;
  if (t < 32768) {
    int u = t & 63, quad = (t >> 6) & 3, ks = (t >> 8) & 3, e = t >> 10;
    int f0 = ks * 32 + quad * 8;
    const float* src = We + e * 8192 + f0 * 64 + u;
    union { unsigned short us[8]; uint4 q; } p;
#pragma unroll
    for (int j = 0; j < 8; j++) p.us[j] = f2bf(src[j * 64]);
    *(uint4*)(wsWe + t * 8) = p.q;
  } else if (t < 32768 + 512) {
    int t2 = t - 32768;
    int l15 = t2 & 15, quad = (t2 >> 4) & 3, ks = (t2 >> 6) & 3, et = t2 >> 8;
    int e = et * 16 + l15, f0 = ks * 32 + quad * 8;
    union { unsigned short us[8]; uint4 q; } p;
#pragma unroll
    for (int j = 0; j < 8; j++) p.us[j] = f2bf(Wg[(f0 + j) * 32 + e]);
    *(uint4*)(wsWg + t2 * 8) = p.q;
  }
}

// ---------------------------------------------------------------------------
// Main: R1 structure EXACTLY (proven 79.8 us total / 13.8 us warm — depth-4
// B ring with &3 indexing; deeper rings get SROA-demoted to scratch, R5-R7).
// ONE addition: an L2-WARMING prologue. After the poison fill + prep, wsWe
// is dirty in remote XCD L2s; main's loop misses the local L2 (~900+ cyc >
// the ring's ~600-cyc horizon -> convoy). Each block DMAs a 64 KB slice
// ((bid&7) of wsWe) + wsWg + be into a 1 KB garbage LDS dump via
// global_load_lds (zero VGPR cost, never read, not DCE'd - intrinsic has
// side effects). ~32 blocks/XCD x 8 slices => local L2 warm by barrier 1
// (its vmcnt(0) drain already waits on the x loads issued alongside).
// ---------------------------------------------------------------------------
__global__ __launch_bounds__(512, 2) void moe_main(
    const float* __restrict__ x,
    const float* __restrict__ bg,
    const float* __restrict__ be,
    const unsigned short* __restrict__ wsWe,
    const unsigned short* __restrict__ wsWg,
    float* __restrict__ out) {
  __shared__ unsigned short Xs[64 * 136];  // padded rows
  __shared__ float Gs[E_DIM][68];          // gate [e][row], padded
  __shared__ __align__(16) char dump[1024];  // DMA garbage sink (never read)

  const int tid  = threadIdx.x;
  const int lane = tid & 63;
  const int wid  = tid >> 6;       // 0..7
  const int quad = lane >> 4;
  const int l15  = lane & 15;
  const int wr   = wid >> 2;       // 0..1 row half
  const int wc   = wid & 3;        // 0..3 u quarter
  const int u    = wc * 16 + l15;
  const int base = blockIdx.x * 64;

  // ---- B ring: prefetch experts 0..2 (needed first; issued before warming
  // so their vmcnt waits don't depend on the warming DMAs)
  bf16x8 bbuf[4][4];
  float bevb[4];
#pragma unroll
  for (int e0 = 0; e0 < 3; e0++) {
#pragma unroll
    for (int ks = 0; ks < 4; ks++)
      bbuf[e0][ks] = *(const bf16x8*)(wsWe + (size_t)((e0 * 4 + ks) * 4 + quad) * 512 + u * 8);
    bevb[e0] = be[e0 * U_DIM + u];
  }

  // ---- L2-warming DMAs: 64 KB slice of wsWe + all of wsWg + all of be.
  // Issued before the x loads are consumed; complete by barrier 1.
  {
    const char* wslice = (const char*)wsWe + (size_t)(blockIdx.x & 7) * 65536;
#pragma unroll
    for (int i = 0; i < 8; i++)
      gload_lds16(wslice + (size_t)i * 8192 + tid * 16, dump);
    gload_lds16((const char*)wsWg + tid * 16, dump);
    gload_lds16((const char*)be + tid * 16, dump);
  }

  // ---- stage X tile (fp32 -> bf16) into LDS: 512 thr x 16 floats = 64x128
  {
    const int row = tid >> 3;
    const int c16 = tid & 7;
    const float4* src = (const float4*)(x + (size_t)(base + row) * F_DIM + c16 * 16);
    float4 v0 = src[0], v1 = src[1], v2 = src[2], v3 = src[3];
    union { unsigned short us[16]; uint4 q[2]; } pk;
    pk.us[0]  = f2bf(v0.x); pk.us[1]  = f2bf(v0.y); pk.us[2]  = f2bf(v0.z); pk.us[3]  = f2bf(v0.w);
    pk.us[4]  = f2bf(v1.x); pk.us[5]  = f2bf(v1.y); pk.us[6]  = f2bf(v1.z); pk.us[7]  = f2bf(v1.w);
    pk.us[8]  = f2bf(v2.x); pk.us[9]  = f2bf(v2.y); pk.us[10] = f2bf(v2.z); pk.us[11] = f2bf(v2.w);
    pk.us[12] = f2bf(v3.x); pk.us[13] = f2bf(v3.y); pk.us[14] = f2bf(v3.z); pk.us[15] = f2bf(v3.w);
    uint4* dst = (uint4*)&Xs[row * 136 + c16 * 16];
    dst[0] = pk.q[0];
    dst[1] = pk.q[1];
  }
  __syncthreads();  // barrier 1: X ready; warming DMAs drained (L2 warm)

  // ---- gate: 8 waves, wave = (rowgroup rg, expert-half et)
  {
    const int rg = wid >> 1;   // 0..3 -> rows rg*16..
    const int et = wid & 1;    // 0..1 -> experts et*16..
    bf16x8 ag[4];
#pragma unroll
    for (int ks = 0; ks < 4; ks++)
      ag[ks] = *(const bf16x8*)&Xs[(rg * 16 + l15) * 136 + ks * 32 + quad * 8];
    floatx4 g = {0.f, 0.f, 0.f, 0.f};
#pragma unroll
    for (int ks = 0; ks < 4; ks++) {
      bf16x8 wb = *(const bf16x8*)(wsWg + (size_t)((et * 4 + ks) * 64 + lane) * 8);
      g = MFMA16(ag[ks], wb, g);
    }
    float bgv = bg[et * 16 + l15];
#pragma unroll
    for (int r = 0; r < 4; r++)
      Gs[et * 16 + l15][rg * 16 + quad * 4 + r] = g[r] + bgv;
  }

  // ---- preload this wave's A fragments (32 rows; X never re-read after)
  bf16x8 a[2][4];
#pragma unroll
  for (int mb = 0; mb < 2; mb++)
#pragma unroll
    for (int ks = 0; ks < 4; ks++)
      a[mb][ks] = *(const bf16x8*)&Xs[(wr * 32 + mb * 16 + l15) * 136 + ks * 32 + quad * 8];
  __syncthreads();  // barrier 2: Gs ready (last barrier)

  float oacc[8];
#pragma unroll
  for (int i = 0; i < 8; i++) oacc[i] = 0.f;

  // ---- gate double-buffer: preload e=0 as float4 rows
  float4 gbuf[2][2];
#pragma unroll
  for (int mb = 0; mb < 2; mb++)
    gbuf[0][mb] = *(const float4*)&Gs[0][wr * 32 + mb * 16 + quad * 4];

  // ---- expert loop: no barriers (R1-proven: &3 ring + unroll 4)
#pragma unroll 4
  for (int e = 0; e < E_DIM; ++e) {
    const int c = e & 3;
    const int gp = e & 1;

    // prefetch B for e+3 into the slot last used by e-1 (consumed)
    if (e + 3 < E_DIM) {
#pragma unroll
      for (int ks = 0; ks < 4; ks++)
        bbuf[(e + 3) & 3][ks] =
            *(const bf16x8*)(wsWe + (size_t)(((e + 3) * 4 + ks) * 4 + quad) * 512 + u * 8);
      bevb[(e + 3) & 3] = be[(e + 3) * U_DIM + u];
    }
    // prefetch gate rows for e+1 (hidden under e's MFMAs)
    if (e + 1 < E_DIM) {
#pragma unroll
      for (int mb = 0; mb < 2; mb++)
        gbuf[gp ^ 1][mb] = *(const float4*)&Gs[e + 1][wr * 32 + mb * 16 + quad * 4];
    }

    const float bev = bevb[c];
    floatx4 h[2];
#pragma unroll
    for (int mb = 0; mb < 2; mb++) h[mb] = {bev, bev, bev, bev};
#pragma unroll
    for (int ks = 0; ks < 4; ks++)
#pragma unroll
      for (int mb = 0; mb < 2; mb++)
        h[mb] = MFMA16(a[mb][ks], bbuf[c][ks], h[mb]);

    // epilogue: out += gate * leaky(h),  leaky(t) = max(t, 0.01t)
#pragma unroll
    for (int mb = 0; mb < 2; mb++) {
      const float4 g4 = gbuf[gp][mb];
      const float gr[4] = {g4.x, g4.y, g4.z, g4.w};
#pragma unroll
      for (int r = 0; r < 4; r++) {
        float t = h[mb][r];
        t = fmaxf(t, 0.01f * t);
        oacc[mb * 4 + r] = fmaf(gr[r], t, oacc[mb * 4 + r]);
      }
    }
  }

  // ---- store
#pragma unroll
  for (int mb = 0; mb < 2; mb++)
#pragma unroll
    for (int r = 0; r < 4; r++)
      out[(size_t)(base + wr * 32 + mb * 16 + quad * 4 + r) * U_DIM + u] = oacc[mb * 4 + r];
}

extern "C" void kernel_launch(void* const* d_in, const int* in_sizes, int n_in,
                              void* d_out, int out_size, void* d_ws, size_t ws_size,
                              hipStream_t stream) {
  const float* x  = (const float*)d_in[0];
  const float* Wg = (const float*)d_in[1];
  const float* bg = (const float*)d_in[2];
  const float* We = (const float*)d_in[3];
  const float* be = (const float*)d_in[4];
  unsigned short* wsWe = (unsigned short*)d_ws;              // 512 KB
  unsigned short* wsWg = wsWe + E_DIM * U_DIM * F_DIM;       // +8 KB
  (void)in_sizes; (void)n_in; (void)out_size; (void)ws_size;

  moe_prep<<<130, 256, 0, stream>>>(Wg, We, wsWe, wsWg);
  moe_main<<<N_TOK / 64, 512, 0, stream>>>(x, bg, be, wsWe, wsWg, (float*)d_out);
}